// Round 13
// baseline (254.383 us; speedup 1.0000x reference)
//
#include <hip/hip_runtime.h>
#include <hip/hip_fp16.h>
#include <hip/hip_bf16.h>

#define M_REAL   54000
#define N_TOT    60000
#define N_EDGE   1000000

typedef __attribute__((ext_vector_type(8)))  short short8;
typedef __attribute__((ext_vector_type(16))) float f32x16;
typedef __attribute__((ext_vector_type(2)))  unsigned int uint2n;
typedef __attribute__((ext_vector_type(4)))  unsigned int uint4n;

// ---------------------------------------------------------------------------
// Build: strided per-dst buckets, COMPACT 8 B slot:
//   .x = raw_row | remap_row<<16      .y = half2(du, dv) (clipped pseudo)
// 8 B slots measured ~3x faster than 16 B (r3 ~18us vs r5+ ~60us): scatter
// write-back cost tracks payload bytes. Exps are recomputed in edge phase
// (VALU idle there; only ~6us/conv — r3/r4 A/B).
// ---------------------------------------------------------------------------
__global__ void build_kernel(const int* __restrict__ row,
                             const int* __restrict__ col,
                             const int* __restrict__ ghost,
                             const float* __restrict__ positions,
                             const float* __restrict__ outpos,
                             const float* __restrict__ supportp,
                             int* __restrict__ counts,
                             uint2n* __restrict__ bucketData,
                             int maxdeg) {
    int e = blockIdx.x * blockDim.x + threadIdx.x;
    if (e >= N_EDGE) return;
    const int c = col[e];
    const int r = row[e];
    const int rm = (r < M_REAL) ? r : ghost[r];
    const float invs = 1.0f / supportp[0];
    float du = (outpos[2 * c]     - positions[2 * r])     * invs;
    float dv = (outpos[2 * c + 1] - positions[2 * r + 1]) * invs;
    du = fminf(fmaxf(du, -1.0f), 1.0f);
    dv = fminf(fmaxf(dv, -1.0f), 1.0f);
    __half2 h2 = __floats2half2_rn(du, dv);
    uint2n d;
    d.x = (unsigned)r | ((unsigned)rm << 16);
    d.y = *reinterpret_cast<unsigned*>(&h2);
    int p = atomicAdd(&counts[c], 1);
    if (p < maxdeg) bucketData[(size_t)c * maxdeg + p] = d;
}

// Zero-fill bucket slots deg..round4(deg) so tail-group loads are safe
// (row 0 gather, contribution masked by true deg in edge). counts keeps
// the TRUE degree.
__global__ void pad_kernel(int* __restrict__ counts,
                           uint2n* __restrict__ bucketData,
                           int maxdeg) {
    int m = blockIdx.x * blockDim.x + threadIdx.x;
    if (m >= M_REAL) return;
    int deg = counts[m];
    if (deg > maxdeg) { deg = maxdeg; counts[m] = maxdeg; }
    int deg4 = (deg + 3) & ~3;
    uint2n z = {0u, 0u};
    for (int p = deg; p < deg4; ++p)
        bucketData[(size_t)m * maxdeg + p] = z;
}

// Convert W0,W1,W2 (f32 [288,32], layout [b*32+k][l]) to TRANSPOSED bf16
// Wt[3][32][288]: Wt[layer][l][k] = W[layer][k][l].
__global__ void wprep_kernel(const float* __restrict__ W0,
                             const float* __restrict__ W1,
                             const float* __restrict__ W2,
                             unsigned short* __restrict__ Wt) {
    int i = blockIdx.x * blockDim.x + threadIdx.x;
    if (i >= 3 * 9216) return;
    const int layer = i / 9216;
    const int rem   = i % 9216;
    const int k     = rem >> 5;
    const int l     = rem & 31;
    const float* src = (layer == 0) ? W0 : (layer == 1 ? W1 : W2);
    __hip_bfloat16 b = __float2bfloat16(src[rem]);
    Wt[layer * 9216 + l * 288 + k] = __builtin_bit_cast(unsigned short, b);
}

// ---------------------------------------------------------------------------
// Edge phase: one dst per half-wave, no LDS, no block sync, f32 gathers,
// 4 edges/iter (4 independent 8B bucket loads + 4 independent gathers in
// flight). Exps recomputed in f32 from half du/dv. Tail masked via true deg.
// Stores T[m,288] bf16, kk = b*32+lane.
// ---------------------------------------------------------------------------
__global__ __launch_bounds__(256) void edge_kernel(
        const float* __restrict__ xin,        // [*,32] f32
        const int*   __restrict__ counts,     // [M] true deg
        const uint2n* __restrict__ bucketData,// [M*maxdeg] strided
        unsigned short* __restrict__ Tb,      // [M,288] bf16
        int use_hi, int maxdeg) {
    const int lane = threadIdx.x & 31;
    const int slot = threadIdx.x >> 5;
    const int m = blockIdx.x * 8 + slot;      // grid exact: M_REAL/8

    float t[9];
#pragma unroll
    for (int b = 0; b < 9; ++b) t[b] = 0.0f;

    const int deg = min(counts[m], maxdeg);
    const uint2n* bd = bucketData + (size_t)m * maxdeg;

    for (int i = 0; i < deg; i += 4) {
        uint2n q[4];
#pragma unroll
        for (int j = 0; j < 4; ++j) q[j] = bd[i + j];
        float x[4];
#pragma unroll
        for (int j = 0; j < 4; ++j) {
            const unsigned rr = use_hi ? (q[j].x >> 16) : (q[j].x & 0xffffu);
            const float xv = xin[(size_t)rr * 32 + lane];
            x[j] = (i + j < deg) ? xv : 0.0f;
        }
#pragma unroll
        for (int j = 0; j < 4; ++j) {
            unsigned qy = q[j].y;
            const float2 D = __half22float2(*reinterpret_cast<const __half2*>(&qy));
            const float du = D.x, dv = D.y;
            const float u0 = __expf(-(du + 1.f) * (du + 1.f));
            const float u1 = __expf(-du * du);
            const float u2 = __expf(-(du - 1.f) * (du - 1.f));
            const float v0 = __expf(-(dv + 1.f) * (dv + 1.f));
            const float v1 = __expf(-dv * dv);
            const float v2 = __expf(-(dv - 1.f) * (dv - 1.f));
            const float xv = x[j];
            const float vx0 = v0 * xv;
            const float vx1 = v1 * xv;
            const float vx2 = v2 * xv;
            t[0] += u0 * vx0; t[1] += u0 * vx1; t[2] += u0 * vx2;
            t[3] += u1 * vx0; t[4] += u1 * vx1; t[5] += u1 * vx2;
            t[6] += u2 * vx0; t[7] += u2 * vx1; t[8] += u2 * vx2;
        }
    }

    unsigned short* tr = Tb + (size_t)m * 288 + lane;
#pragma unroll
    for (int b = 0; b < 9; ++b) {
        __hip_bfloat16 h = __float2bfloat16(t[b]);
        tr[b * 32] = __builtin_bit_cast(unsigned short, h);
    }
}

// ---------------------------------------------------------------------------
// GEMM (r9-proven): out[M,32] = T[M,288](bf16) x W[288,32](bf16), f32 accum.
// One 32-row tile per wave, 1688 tiles. 18 A b128 + 18 B b128 then 18 MFMA.
// A frag: row = lane&31, k = (lane>>5)*8 + j. B frag: col = lane&31, same k.
// C/D: col = lane&31, row = (reg&3) + 8*(reg>>2) + 4*(lane>>5).
// ---------------------------------------------------------------------------
__global__ __launch_bounds__(256, 2) void gemm_kernel(
        const unsigned short* __restrict__ Tb,  // [M,288] bf16
        const unsigned short* __restrict__ Wt,  // [32,288] bf16 (transposed)
        float* __restrict__ yout,               // [M,32] f32
        int act) {
    const int wave = threadIdx.x >> 6;
    const int lane = threadIdx.x & 63;
    const int col  = lane & 31;
    const int kh   = lane >> 5;
    const int m0   = (blockIdx.x * 4 + wave) * 32;

    const int row  = m0 + col;
    const int rowc = (row < M_REAL) ? row : (M_REAL - 1);
    const uint4n* a = reinterpret_cast<const uint4n*>(Tb + (size_t)rowc * 288) + kh;
    const uint4n* b = reinterpret_cast<const uint4n*>(Wt + (size_t)col * 288) + kh;

    f32x16 acc = {};
#pragma unroll
    for (int s = 0; s < 18; ++s) {
        union { uint4n u; short8 v; } av, bv;
        av.u = a[s * 2];
        bv.u = b[s * 2];
        acc = __builtin_amdgcn_mfma_f32_32x32x16_bf16(av.v, bv.v, acc, 0, 0, 0);
    }

#pragma unroll
    for (int r = 0; r < 16; ++r) {
        const int rr = (r & 3) + 8 * (r >> 2) + 4 * kh;
        const int om = m0 + rr;
        float v = acc[r];
        if (act) v = fmaxf(v, 0.0f);
        if (om < M_REAL) yout[om * 32 + col] = v;
    }
}

// Fill ghost rows of the final output: out[M+i] = out[ghost[M+i]]
__global__ void ghost_kernel(const int* __restrict__ ghost,
                             float* __restrict__ out) {
    int idx = blockIdx.x * blockDim.x + threadIdx.x;
    if (idx >= (N_TOT - M_REAL) * 32) return;
    int i = idx >> 5;
    int k = idx & 31;
    int g = ghost[M_REAL + i];
    out[(M_REAL + i) * 32 + k] = out[g * 32 + k];
}

extern "C" void kernel_launch(void* const* d_in, const int* in_sizes, int n_in,
                              void* d_out, int out_size, void* d_ws, size_t ws_size,
                              hipStream_t stream) {
    const float* positions = (const float*)d_in[0];
    const float* features  = (const float*)d_in[1];
    const float* outpos    = (const float*)d_in[2];
    const int*   ghost     = (const int*)d_in[3];
    const float* support   = (const float*)d_in[4];
    const int*   edge      = (const int*)d_in[5];   // [2,E]
    const float* W0        = (const float*)d_in[6];
    const float* W1        = (const float*)d_in[7];
    const float* W2        = (const float*)d_in[8];
    float* out = (float*)d_out;

    auto al = [](size_t x) { return (x + 255) & ~(size_t)255; };
    const size_t countsB = al((size_t)M_REAL * 4);
    const size_t TbB     = al((size_t)M_REAL * 288 * 2);
    const size_t WtB     = al((size_t)3 * 9216 * 2);
    const size_t outB    = al((size_t)M_REAL * 32 * 4);
    const size_t need64  = countsB + (size_t)M_REAL * 64 * 8 + TbB + WtB + outB;
    const int maxdeg = (ws_size >= need64) ? 64 : 48;

    char* ws = (char*)d_ws;
    int*            counts     = (int*)ws;            ws += countsB;
    uint2n*         bucketData = (uint2n*)ws;         ws += (size_t)M_REAL * maxdeg * 8;
    unsigned short* Tb         = (unsigned short*)ws; ws += TbB;
    unsigned short* Wt         = (unsigned short*)ws; ws += WtB;
    float*          out1       = (float*)ws;
    float*          out0       = out;   // reuse d_out real-row region as scratch

    const int* erow = edge;
    const int* ecol = edge + N_EDGE;

    (void)hipMemsetAsync(counts, 0, (size_t)M_REAL * 4, stream);
    build_kernel<<<(N_EDGE + 255) / 256, 256, 0, stream>>>(
        erow, ecol, ghost, positions, outpos, support, counts, bucketData, maxdeg);
    pad_kernel<<<(M_REAL + 255) / 256, 256, 0, stream>>>(counts, bucketData, maxdeg);
    wprep_kernel<<<(3 * 9216 + 255) / 256, 256, 0, stream>>>(W0, W1, W2, Wt);

    const int egrid = M_REAL / 8;                 // 6750, exact
    const int ggrid = 422;                        // 422*4 waves = 1688 tiles

    // layer 0: gather raw rows (lo16) from f32 features
    edge_kernel<<<egrid, 256, 0, stream>>>(features, counts, bucketData, Tb, 0, maxdeg);
    gemm_kernel<<<ggrid, 256, 0, stream>>>(Tb, Wt, out0, 1);
    // layer 1: gather remapped rows (hi16) from out0
    edge_kernel<<<egrid, 256, 0, stream>>>(out0, counts, bucketData, Tb, 1, maxdeg);
    gemm_kernel<<<ggrid, 256, 0, stream>>>(Tb, Wt + 9216, out1, 1);
    // layer 2: no act, write real rows of d_out
    edge_kernel<<<egrid, 256, 0, stream>>>(out1, counts, bucketData, Tb, 1, maxdeg);
    gemm_kernel<<<ggrid, 256, 0, stream>>>(Tb, Wt + 2 * 9216, out, 0);

    ghost_kernel<<<((N_TOT - M_REAL) * 32 + 255) / 256, 256, 0, stream>>>(ghost, out);
}